// Round 6
// baseline (69.705 us; speedup 1.0000x reference)
//
#include <hip/hip_runtime.h>

#define SEQ 2048
#define DMODEL 1024
#define DHEAD 64
#define NROWS 16384
#define ATT_SC2 0.0450842300667f   // (1/sqrt(1024)) * log2(e), for exp2f

typedef __attribute__((ext_vector_type(8))) short bf16x8;
typedef __attribute__((ext_vector_type(4))) float f32x4;
typedef __attribute__((ext_vector_type(4))) unsigned int u32x4;
typedef __attribute__((ext_vector_type(4))) unsigned short u16x4;
typedef __attribute__((ext_vector_type(4))) float fl4;

#define MFMA16(a,b,c) __builtin_amdgcn_mfma_f32_16x16x32_bf16((a),(b),(c),0,0,0)
#define GLL16(g, l) __builtin_amdgcn_global_load_lds( \
    (const __attribute__((address_space(1))) void*)(g), \
    (__attribute__((address_space(3))) void*)(l), 16, 0, 0)

__device__ __forceinline__ unsigned short f2bf(float f) {
    union { float f; unsigned int u; } v; v.f = f;
    unsigned int u = v.u;
    unsigned int r = u + 0x7fffu + ((u >> 16) & 1u);
    return (unsigned short)(r >> 16);
}

// packed f32x2 -> bf16x2 (RNE) — T12 primitive, no builtin on gfx950
__device__ __forceinline__ unsigned int cvtpk(float lo, float hi) {
    unsigned int d;
    asm volatile("v_cvt_pk_bf16_f32 %0, %1, %2" : "=v"(d) : "v"(lo), "v"(hi));
    return d;
}

// ---------------- kernel 0: convert weights to bf16 ----------------
__global__ __launch_bounds__(256) void k_cvt(
    const float* __restrict__ Wq, const float* __restrict__ Wk,
    const float* __restrict__ Wv, const float* __restrict__ Wo,
    unsigned short* __restrict__ Wb,    // [192][1024] (Wq;Wk;Wv)
    unsigned short* __restrict__ Wob)   // [1024][64]
{
    int i4 = blockIdx.x * 256 + threadIdx.x;
    const int W1 = 16384;
    const float* src; unsigned short* dst; int off;
    if (i4 < 3 * W1) {
        int which = i4 / W1;
        off = i4 - which * W1;
        src = (which == 0) ? Wq : (which == 1) ? Wk : Wv;
        dst = Wb + (size_t)which * 65536;
    } else {
        off = i4 - 3 * W1; src = Wo; dst = Wob;
    }
    fl4 v = reinterpret_cast<const fl4*>(src)[off];
    u16x4 o;
    o[0] = f2bf(v[0]); o[1] = f2bf(v[1]); o[2] = f2bf(v[2]); o[3] = f2bf(v[3]);
    reinterpret_cast<u16x4*>(dst)[off] = o;
}

// ---------------- kernel A: QKV projection, async pipelined ----------------
__global__ __launch_bounds__(256) void k_qkv(
    const float* __restrict__ x,
    const unsigned short* __restrict__ Wb,
    unsigned short* __restrict__ Qb,
    unsigned short* __restrict__ Kb,
    unsigned short* __restrict__ Vt)
{
    __shared__ __align__(16) char smem[81920];

    int tid = threadIdx.x;
    int wave = tid >> 6, lane = tid & 63, g = lane >> 4, lr = lane & 15;
    int mbase = blockIdx.x * 64;

    const float* xsrc[4];
#pragma unroll
    for (int j = 0; j < 4; ++j) {
        int ci = (wave * 4 + j) * 64 + lane;
        int row = ci >> 4, c = ci & 15, cg = c ^ (row & 7);
        xsrc[j] = x + (size_t)(mbase + row) * DMODEL + cg * 4;
    }
    const unsigned short* wsrc[6];
#pragma unroll
    for (int j = 0; j < 6; ++j) {
        int ci = (wave * 6 + j) * 64 + lane;
        int row = ci >> 3, c = ci & 7, cg = c ^ (row & 7);
        wsrc[j] = Wb + (size_t)row * DMODEL + cg * 8;
    }

    f32x4 acc[12];
#pragma unroll
    for (int f = 0; f < 12; ++f) acc[f] = (f32x4){0.f, 0.f, 0.f, 0.f};

#pragma unroll
    for (int j = 0; j < 4; ++j) GLL16(xsrc[j], smem + (wave * 4 + j) * 1024);
#pragma unroll
    for (int j = 0; j < 6; ++j) GLL16(wsrc[j], smem + 32768 + (wave * 6 + j) * 1024);

    for (int ks = 0; ks < 16; ++ks) {
        int cur = ks & 1;
        if (ks < 15) {
            int nb = cur ^ 1;
#pragma unroll
            for (int j = 0; j < 4; ++j)
                GLL16(xsrc[j] + (ks + 1) * 64, smem + nb * 16384 + (wave * 4 + j) * 1024);
#pragma unroll
            for (int j = 0; j < 6; ++j)
                GLL16(wsrc[j] + (ks + 1) * 64, smem + 32768 + nb * 24576 + (wave * 6 + j) * 1024);
            asm volatile("s_waitcnt vmcnt(10)" ::: "memory");
        } else {
            asm volatile("s_waitcnt vmcnt(0)" ::: "memory");
        }
        __builtin_amdgcn_s_barrier();
        asm volatile("" ::: "memory");

        const float* Xf = (const float*)(smem + cur * 16384);
        const unsigned short* Wf = (const unsigned short*)(smem + 32768 + cur * 24576);
        int arow = wave * 16 + lr;
#pragma unroll
        for (int kc = 0; kc < 2; ++kc) {
            int c0 = (kc * 8 + g * 2) ^ (lr & 7);
            int c1 = (kc * 8 + g * 2 + 1) ^ (lr & 7);
            fl4 xa = *(const fl4*)&Xf[arow * 64 + c0 * 4];
            fl4 xb = *(const fl4*)&Xf[arow * 64 + c1 * 4];
            union { unsigned int u[4]; bf16x8 v; } a;
            a.u[0] = cvtpk(xa[0], xa[1]); a.u[1] = cvtpk(xa[2], xa[3]);
            a.u[2] = cvtpk(xb[0], xb[1]); a.u[3] = cvtpk(xb[2], xb[3]);
            __builtin_amdgcn_s_setprio(1);
#pragma unroll
            for (int f = 0; f < 12; ++f) {
                int brow = f * 16 + lr;
                int cb = (kc * 4 + g) ^ (lr & 7);
                bf16x8 b = *(const bf16x8*)&Wf[brow * 64 + cb * 8];
                acc[f] = MFMA16(a.v, b, acc[f]);
            }
            __builtin_amdgcn_s_setprio(0);
        }
        asm volatile("" ::: "memory");
        __builtin_amdgcn_s_barrier();
    }

    int mrow = mbase + wave * 16 + g * 4;
#pragma unroll
    for (int f = 0; f < 8; ++f) {
        int col = f * 16 + lr;
#pragma unroll
        for (int r = 0; r < 4; ++r) {
            unsigned short bv = f2bf(acc[f][r]);
            if (f < 4) Qb[(size_t)(mrow + r) * DHEAD + col] = bv;
            else       Kb[(size_t)(mrow + r) * DHEAD + col - 64] = bv;
        }
    }
    unsigned short* tmp = (unsigned short*)smem;  // [64][72]
#pragma unroll
    for (int f = 8; f < 12; ++f) {
        int h = (f - 8) * 16 + lr;
#pragma unroll
        for (int r = 0; r < 4; ++r)
            tmp[(wave * 16 + g * 4 + r) * 72 + h] = f2bf(acc[f][r]);
    }
    __syncthreads();
    int b = mbase >> 11, sbase = mbase & 2047;
    int h = tid >> 2, sc = tid & 3;
    u32x4 o0, o1;
#pragma unroll
    for (int j = 0; j < 4; ++j) {
        o0[j] = (unsigned int)tmp[(sc * 16 + 2 * j) * 72 + h] |
                ((unsigned int)tmp[(sc * 16 + 2 * j + 1) * 72 + h] << 16);
        o1[j] = (unsigned int)tmp[(sc * 16 + 8 + 2 * j) * 72 + h] |
                ((unsigned int)tmp[(sc * 16 + 9 + 2 * j) * 72 + h] << 16);
    }
    size_t off = ((size_t)(b * 64 + h)) * SEQ + sbase + sc * 16;
    *reinterpret_cast<u32x4*>(&Vt[off]) = o0;
    *reinterpret_cast<u32x4*>(&Vt[off + 8]) = o1;
}

// ---------------- kernel B: causal flash attention ----------------
// QBLK=64 (4 waves x 16 q-rows), KVBLK=64, 4-way kv-split (t mod 4).
// Grid 1024 = 4 chunks x (32 qt x 8 b); quarter k handles chunk k with qt
// descending (k even) / ascending (k odd) so each CU's 4 blocks sum ~equal.
// Fixed-max softmax (exp2), per-lane deferred l. Wave-uniform mask skip.
// LDS 40KB: K 2x8KB @0, V 2x8KB @16384, P 4x2KB @32768 -> 4 blocks/CU.
__global__ __launch_bounds__(256) void k_attn(
    const unsigned short* __restrict__ Qb,
    const unsigned short* __restrict__ Kb,
    const unsigned short* __restrict__ Vt,
    float* __restrict__ Op,    // [4][16384][64]
    float* __restrict__ Lp)    // [4][16384]
{
    __shared__ __align__(16) char smem[40960];

    int tid = threadIdx.x;
    int wave = tid >> 6, lane = tid & 63, g = lane >> 4, lr = lane & 15;
    int bid = blockIdx.x;
    int chunk = bid >> 8;              // 0..3: this block's kv residue class
    int idx = bid & 255;
    int hv = idx >> 3;                 // 0..31
    int qt = (chunk & 1) ? hv : 31 - hv;   // balance heavy/light across CUs
    int b = idx & 7;
    int my_nt = (qt >= chunk) ? ((qt - chunk) >> 2) + 1 : 0;  // tiles t=chunk,chunk+4,...<=qt
    int qw = qt * 64 + wave * 16;      // this wave's first q-row
    size_t qrowbase = (size_t)(b * SEQ) + qw;

    bf16x8 aq[2];
#pragma unroll
    for (int kc = 0; kc < 2; ++kc)
        aq[kc] = *reinterpret_cast<const bf16x8*>(
            &Qb[(qrowbase + lr) * DHEAD + kc * 32 + g * 8]);

    // staging sources (pre-swizzled); 256 thr x 16B x 2 = 8KB per operand
    const unsigned short* ksrc[2];
    const unsigned short* vsrc[2];
#pragma unroll
    for (int j = 0; j < 2; ++j) {
        int ci = j * 256 + tid;
        int row = ci >> 3, c = ci & 7, cg = c ^ (row & 7);
        ksrc[j] = Kb + ((size_t)(b * SEQ) + row) * DHEAD + cg * 8;
        vsrc[j] = Vt + ((size_t)(b * DHEAD) + row) * SEQ + cg * 8;
    }

    float l_part[4];
    f32x4 of[4];
#pragma unroll
    for (int r = 0; r < 4; ++r) l_part[r] = 0.f;
#pragma unroll
    for (int f = 0; f < 4; ++f) of[f] = (f32x4){0.f, 0.f, 0.f, 0.f};

    if (my_nt > 0) {
        // prologue: stage tile t=chunk into buf 0
#pragma unroll
        for (int j = 0; j < 2; ++j)
            GLL16(ksrc[j] + (size_t)chunk * 64 * DHEAD, smem + j * 4096 + wave * 1024);
#pragma unroll
        for (int j = 0; j < 2; ++j)
            GLL16(vsrc[j] + chunk * 64, smem + 16384 + j * 4096 + wave * 1024);

        for (int i = 0; i < my_nt; ++i) {
            int t = chunk + 4 * i;
            int cur = i & 1;
            int kvb = t * 64;
            if (i + 1 < my_nt) {
                int nb = cur ^ 1;
#pragma unroll
                for (int j = 0; j < 2; ++j)
                    GLL16(ksrc[j] + (size_t)(t + 4) * 64 * DHEAD,
                          smem + nb * 8192 + j * 4096 + wave * 1024);
#pragma unroll
                for (int j = 0; j < 2; ++j)
                    GLL16(vsrc[j] + (t + 4) * 64,
                          smem + 16384 + nb * 8192 + j * 4096 + wave * 1024);
                asm volatile("s_waitcnt vmcnt(4)" ::: "memory");
            } else {
                asm volatile("s_waitcnt vmcnt(0)" ::: "memory");
            }
            __builtin_amdgcn_s_barrier();
            asm volatile("" ::: "memory");

            if (kvb <= qw + 15) {   // wave-uniform: skip fully-masked tiles
                const unsigned short* Kl = (const unsigned short*)(smem + cur * 8192);
                const unsigned short* Vl = (const unsigned short*)(smem + 16384 + cur * 8192);
                unsigned short* Pl = (unsigned short*)(smem + 32768) + wave * 1024;

                // S = Q K^T
                f32x4 s[4];
#pragma unroll
                for (int f = 0; f < 4; ++f) s[f] = (f32x4){0.f, 0.f, 0.f, 0.f};
                __builtin_amdgcn_s_setprio(1);
#pragma unroll
                for (int kc = 0; kc < 2; ++kc) {
#pragma unroll
                    for (int f = 0; f < 4; ++f) {
                        int brow = f * 16 + lr;
                        int cb = (kc * 4 + g) ^ (lr & 7);
                        bf16x8 bk = *(const bf16x8*)&Kl[brow * 64 + cb * 8];
                        s[f] = MFMA16(aq[kc], bk, s[f]);
                    }
                }
                __builtin_amdgcn_s_setprio(0);

                if (kvb + 63 <= qw) {
                    // fully unmasked: no compare/select needed
#pragma unroll
                    for (int f = 0; f < 4; ++f)
#pragma unroll
                        for (int r = 0; r < 4; ++r) {
                            float p = exp2f(s[f][r] * ATT_SC2);
                            s[f][r] = p;
                            l_part[r] += p;
                        }
                } else {
                    // diagonal tile: causal mask
#pragma unroll
                    for (int f = 0; f < 4; ++f) {
                        int kvg = kvb + f * 16 + lr;
#pragma unroll
                        for (int r = 0; r < 4; ++r) {
                            int qr = qw + g * 4 + r;
                            float p = exp2f(s[f][r] * ATT_SC2);
                            p = (kvg > qr) ? 0.f : p;
                            s[f][r] = p;
                            l_part[r] += p;
                        }
                    }
                }
                // P -> per-wave LDS (swizzled), bf16
#pragma unroll
                for (int f = 0; f < 4; ++f) {
#pragma unroll
                    for (int r = 0; r < 4; ++r) {
                        int row = g * 4 + r, col = f * 16 + lr;
                        int ch = (col >> 3) ^ (row & 7);
                        Pl[row * 64 + ch * 8 + (col & 7)] = f2bf(s[f][r]);
                    }
                }
                // O += P V
#pragma unroll
                for (int kc = 0; kc < 2; ++kc) {
                    int cp = (kc * 4 + g) ^ (lr & 7);
                    bf16x8 ap = *(const bf16x8*)&Pl[lr * 64 + cp * 8];
                    __builtin_amdgcn_s_setprio(1);
#pragma unroll
                    for (int fd = 0; fd < 4; ++fd) {
                        int vrow = fd * 16 + lr;
                        int cv = (kc * 4 + g) ^ (lr & 7);
                        bf16x8 bv = *(const bf16x8*)&Vl[vrow * 64 + cv * 8];
                        of[fd] = MFMA16(ap, bv, of[fd]);
                    }
                    __builtin_amdgcn_s_setprio(0);
                }
            }
            asm volatile("" ::: "memory");
            __builtin_amdgcn_s_barrier();
        }
    }

    // epilogue: reduce l across the 16-lane group, store partials
    float* opb = Op + ((size_t)chunk * NROWS + qrowbase) * 64;
#pragma unroll
    for (int r = 0; r < 4; ++r) {
        float ls = l_part[r];
        ls += __shfl_xor(ls, 1); ls += __shfl_xor(ls, 2);
        ls += __shfl_xor(ls, 4); ls += __shfl_xor(ls, 8);
        if (lr == 0)
            Lp[(size_t)chunk * NROWS + qrowbase + g * 4 + r] = ls;
#pragma unroll
        for (int fd = 0; fd < 4; ++fd)
            opb[(g * 4 + r) * 64 + fd * 16 + lr] = of[fd][r];
    }
}

// ---------------- kernel C: combine 4 partials + output projection ---------
__global__ __launch_bounds__(256) void k_oproj(
    const float* __restrict__ Op,
    const float* __restrict__ Lp,
    const unsigned short* __restrict__ Wob,
    float* __restrict__ out)
{
    __shared__ __align__(16) unsigned short Wl[256 * 64];
    int tid = threadIdx.x;
    int wave = tid >> 6, lane = tid & 63, g = lane >> 4, lr = lane & 15;
    int mb = blockIdx.x * 64, nb = blockIdx.y * 256;

#pragma unroll
    for (int p = 0; p < 8; ++p) {
        int idx = p * 256 + tid;
        int row = idx >> 3, c = idx & 7;
        int ch = c ^ (row & 7);
        u32x4 v = *reinterpret_cast<const u32x4*>(
            &Wob[(size_t)(nb + row) * DHEAD + c * 8]);
        *reinterpret_cast<u32x4*>(&Wl[row * 64 + ch * 8]) = v;
    }
    __syncthreads();

    int row = mb + wave * 16 + lr;
    float inv = 1.0f / (Lp[row] + Lp[NROWS + row] +
                        Lp[2 * NROWS + row] + Lp[3 * NROWS + row]);
    bf16x8 ao[2];
#pragma unroll
    for (int kc = 0; kc < 2; ++kc) {
        float v[8];
#pragma unroll
        for (int j = 0; j < 8; ++j) v[j] = 0.f;
#pragma unroll
        for (int c = 0; c < 4; ++c) {
            const float* p = &Op[((size_t)c * NROWS + row) * 64 + kc * 32 + g * 8];
            fl4 a = *(const fl4*)p, bq = *(const fl4*)(p + 4);
#pragma unroll
            for (int j = 0; j < 4; ++j) { v[j] += a[j]; v[j + 4] += bq[j]; }
        }
        union { unsigned int u[4]; bf16x8 w; } a;
        a.u[0] = cvtpk(v[0] * inv, v[1] * inv);
        a.u[1] = cvtpk(v[2] * inv, v[3] * inv);
        a.u[2] = cvtpk(v[4] * inv, v[5] * inv);
        a.u[3] = cvtpk(v[6] * inv, v[7] * inv);
        ao[kc] = a.w;
    }

    f32x4 acc[16];
#pragma unroll
    for (int f = 0; f < 16; ++f) acc[f] = (f32x4){0.f, 0.f, 0.f, 0.f};
#pragma unroll
    for (int kc = 0; kc < 2; ++kc) {
        __builtin_amdgcn_s_setprio(1);
#pragma unroll
        for (int f = 0; f < 16; ++f) {
            int brow = f * 16 + lr;
            int cb = (kc * 4 + g) ^ (brow & 7);
            bf16x8 bw = *reinterpret_cast<const bf16x8*>(&Wl[brow * 64 + cb * 8]);
            acc[f] = MFMA16(ao[kc], bw, acc[f]);
        }
        __builtin_amdgcn_s_setprio(0);
    }
    int mrow = mb + wave * 16 + g * 4;
#pragma unroll
    for (int f = 0; f < 16; ++f) {
#pragma unroll
        for (int r = 0; r < 4; ++r)
            out[(size_t)(mrow + r) * DMODEL + nb + f * 16 + lr] = acc[f][r];
    }
}

extern "C" void kernel_launch(void* const* d_in, const int* in_sizes, int n_in,
                              void* d_out, int out_size, void* d_ws, size_t ws_size,
                              hipStream_t stream) {
    const float* x  = (const float*)d_in[0];
    const float* Wq = (const float*)d_in[1];
    const float* Wk = (const float*)d_in[2];
    const float* Wv = (const float*)d_in[3];
    const float* Wo = (const float*)d_in[4];
    float* out = (float*)d_out;

    unsigned short* Wb  = (unsigned short*)d_ws;   // 192*1024
    unsigned short* Wob = Wb + 196608;             // 1024*64
    unsigned short* Qb  = Wob + 65536;             // 16384*64
    unsigned short* Kb  = Qb + 1048576;
    unsigned short* Vt  = Kb + 1048576;            // [8][64][2048]
    float* Op = (float*)(Vt + 1048576);            // [4][16384][64]
    float* Lp = Op + 4 * NROWS * 64;               // [4][16384]

    k_cvt<<<256, 256, 0, stream>>>(Wq, Wk, Wv, Wo, Wb, Wob);
    k_qkv<<<256, 256, 0, stream>>>(x, Wb, Qb, Kb, Vt);
    k_attn<<<1024, 256, 0, stream>>>(Qb, Kb, Vt, Op, Lp);
    k_oproj<<<dim3(256, 4), 256, 0, stream>>>(Op, Lp, Wob, out);
}

// Round 7
// 67.627 us; speedup vs baseline: 1.0307x; 1.0307x over previous
//
#include <hip/hip_runtime.h>

#define SEQ 2048
#define DMODEL 1024
#define DHEAD 64
#define NROWS 16384
#define ATT_SC2 0.0450842300667f   // (1/sqrt(1024)) * log2(e), for exp2f

typedef __attribute__((ext_vector_type(8))) short bf16x8;
typedef __attribute__((ext_vector_type(4))) float f32x4;
typedef __attribute__((ext_vector_type(4))) unsigned int u32x4;
typedef __attribute__((ext_vector_type(4))) unsigned short u16x4;
typedef __attribute__((ext_vector_type(4))) float fl4;

#define MFMA16(a,b,c) __builtin_amdgcn_mfma_f32_16x16x32_bf16((a),(b),(c),0,0,0)
#define GLL16(g, l) __builtin_amdgcn_global_load_lds( \
    (const __attribute__((address_space(1))) void*)(g), \
    (__attribute__((address_space(3))) void*)(l), 16, 0, 0)

__device__ __forceinline__ unsigned short f2bf(float f) {
    union { float f; unsigned int u; } v; v.f = f;
    unsigned int u = v.u;
    unsigned int r = u + 0x7fffu + ((u >> 16) & 1u);
    return (unsigned short)(r >> 16);
}

// packed f32x2 -> bf16x2 (RNE) — T12 primitive, no builtin on gfx950
__device__ __forceinline__ unsigned int cvtpk(float lo, float hi) {
    unsigned int d;
    asm volatile("v_cvt_pk_bf16_f32 %0, %1, %2" : "=v"(d) : "v"(lo), "v"(hi));
    return d;
}

// ---------------- kernel 0: convert weights to bf16 ----------------
__global__ __launch_bounds__(256) void k_cvt(
    const float* __restrict__ Wq, const float* __restrict__ Wk,
    const float* __restrict__ Wv, const float* __restrict__ Wo,
    unsigned short* __restrict__ Wb,    // [192][1024] (Wq;Wk;Wv)
    unsigned short* __restrict__ Wob)   // [1024][64]
{
    int i4 = blockIdx.x * 256 + threadIdx.x;
    const int W1 = 16384;
    const float* src; unsigned short* dst; int off;
    if (i4 < 3 * W1) {
        int which = i4 / W1;
        off = i4 - which * W1;
        src = (which == 0) ? Wq : (which == 1) ? Wk : Wv;
        dst = Wb + (size_t)which * 65536;
    } else {
        off = i4 - 3 * W1; src = Wo; dst = Wob;
    }
    fl4 v = reinterpret_cast<const fl4*>(src)[off];
    u16x4 o;
    o[0] = f2bf(v[0]); o[1] = f2bf(v[1]); o[2] = f2bf(v[2]); o[3] = f2bf(v[3]);
    reinterpret_cast<u16x4*>(dst)[off] = o;
}

// ---------------- kernel A: QKV projection, async pipelined ----------------
__global__ __launch_bounds__(256) void k_qkv(
    const float* __restrict__ x,
    const unsigned short* __restrict__ Wb,
    unsigned short* __restrict__ Qb,
    unsigned short* __restrict__ Kb,
    unsigned short* __restrict__ Vt)
{
    __shared__ __align__(16) char smem[81920];

    int tid = threadIdx.x;
    int wave = tid >> 6, lane = tid & 63, g = lane >> 4, lr = lane & 15;
    int mbase = blockIdx.x * 64;

    const float* xsrc[4];
#pragma unroll
    for (int j = 0; j < 4; ++j) {
        int ci = (wave * 4 + j) * 64 + lane;
        int row = ci >> 4, c = ci & 15, cg = c ^ (row & 7);
        xsrc[j] = x + (size_t)(mbase + row) * DMODEL + cg * 4;
    }
    const unsigned short* wsrc[6];
#pragma unroll
    for (int j = 0; j < 6; ++j) {
        int ci = (wave * 6 + j) * 64 + lane;
        int row = ci >> 3, c = ci & 7, cg = c ^ (row & 7);
        wsrc[j] = Wb + (size_t)row * DMODEL + cg * 8;
    }

    f32x4 acc[12];
#pragma unroll
    for (int f = 0; f < 12; ++f) acc[f] = (f32x4){0.f, 0.f, 0.f, 0.f};

#pragma unroll
    for (int j = 0; j < 4; ++j) GLL16(xsrc[j], smem + (wave * 4 + j) * 1024);
#pragma unroll
    for (int j = 0; j < 6; ++j) GLL16(wsrc[j], smem + 32768 + (wave * 6 + j) * 1024);

    for (int ks = 0; ks < 16; ++ks) {
        int cur = ks & 1;
        if (ks < 15) {
            int nb = cur ^ 1;
#pragma unroll
            for (int j = 0; j < 4; ++j)
                GLL16(xsrc[j] + (ks + 1) * 64, smem + nb * 16384 + (wave * 4 + j) * 1024);
#pragma unroll
            for (int j = 0; j < 6; ++j)
                GLL16(wsrc[j] + (ks + 1) * 64, smem + 32768 + nb * 24576 + (wave * 6 + j) * 1024);
            asm volatile("s_waitcnt vmcnt(10)" ::: "memory");
        } else {
            asm volatile("s_waitcnt vmcnt(0)" ::: "memory");
        }
        __builtin_amdgcn_s_barrier();
        asm volatile("" ::: "memory");

        const float* Xf = (const float*)(smem + cur * 16384);
        const unsigned short* Wf = (const unsigned short*)(smem + 32768 + cur * 24576);
        int arow = wave * 16 + lr;
#pragma unroll
        for (int kc = 0; kc < 2; ++kc) {
            int c0 = (kc * 8 + g * 2) ^ (lr & 7);
            int c1 = (kc * 8 + g * 2 + 1) ^ (lr & 7);
            fl4 xa = *(const fl4*)&Xf[arow * 64 + c0 * 4];
            fl4 xb = *(const fl4*)&Xf[arow * 64 + c1 * 4];
            union { unsigned int u[4]; bf16x8 v; } a;
            a.u[0] = cvtpk(xa[0], xa[1]); a.u[1] = cvtpk(xa[2], xa[3]);
            a.u[2] = cvtpk(xb[0], xb[1]); a.u[3] = cvtpk(xb[2], xb[3]);
            __builtin_amdgcn_s_setprio(1);
#pragma unroll
            for (int f = 0; f < 12; ++f) {
                int brow = f * 16 + lr;
                int cb = (kc * 4 + g) ^ (lr & 7);
                bf16x8 b = *(const bf16x8*)&Wf[brow * 64 + cb * 8];
                acc[f] = MFMA16(a.v, b, acc[f]);
            }
            __builtin_amdgcn_s_setprio(0);
        }
        asm volatile("" ::: "memory");
        __builtin_amdgcn_s_barrier();
    }

    int mrow = mbase + wave * 16 + g * 4;
#pragma unroll
    for (int f = 0; f < 8; ++f) {
        int col = f * 16 + lr;
#pragma unroll
        for (int r = 0; r < 4; ++r) {
            unsigned short bv = f2bf(acc[f][r]);
            if (f < 4) Qb[(size_t)(mrow + r) * DHEAD + col] = bv;
            else       Kb[(size_t)(mrow + r) * DHEAD + col - 64] = bv;
        }
    }
    unsigned short* tmp = (unsigned short*)smem;  // [64][72]
#pragma unroll
    for (int f = 8; f < 12; ++f) {
        int h = (f - 8) * 16 + lr;
#pragma unroll
        for (int r = 0; r < 4; ++r)
            tmp[(wave * 16 + g * 4 + r) * 72 + h] = f2bf(acc[f][r]);
    }
    __syncthreads();
    int b = mbase >> 11, sbase = mbase & 2047;
    int h = tid >> 2, sc = tid & 3;
    u32x4 o0, o1;
#pragma unroll
    for (int j = 0; j < 4; ++j) {
        o0[j] = (unsigned int)tmp[(sc * 16 + 2 * j) * 72 + h] |
                ((unsigned int)tmp[(sc * 16 + 2 * j + 1) * 72 + h] << 16);
        o1[j] = (unsigned int)tmp[(sc * 16 + 8 + 2 * j) * 72 + h] |
                ((unsigned int)tmp[(sc * 16 + 9 + 2 * j) * 72 + h] << 16);
    }
    size_t off = ((size_t)(b * 64 + h)) * SEQ + sbase + sc * 16;
    *reinterpret_cast<u32x4*>(&Vt[off]) = o0;
    *reinterpret_cast<u32x4*>(&Vt[off + 8]) = o1;
}

// ---------------- kernel B: fused causal attention + output projection -----
// Grid 256 = 32 pair-ids x 8 batches (1 block/CU, uniform work: each block
// owns q-tiles {pid, 63-pid} of 32 rows -> 33-34 kv tiles total, every pid).
// Block = 4 waves; wave-pair p computes kv tiles t==p (mod 2) from a shared
// double-buffered 2-tile stage. Fixed-max softmax (exp2), deferred l.
// Epilogue per q-tile: combine pair partials in LDS ([32][68] f32 padded),
// normalize, cvt to bf16 A-frags, then out[32][1024] = O * Wob^T with
// B-frags read directly from L2 (no LDS staging).
// LDS 72KB: stage 2x32KB @0 (K even/odd 8KB+8KB, V even/odd 8KB+8KB), P 8KB @65536.
__global__ __launch_bounds__(256) void k_fused(
    const unsigned short* __restrict__ Qb,
    const unsigned short* __restrict__ Kb,
    const unsigned short* __restrict__ Vt,
    const unsigned short* __restrict__ Wob,
    float* __restrict__ out)
{
    __shared__ __align__(16) char smem[73728];

    int tid = threadIdx.x;
    int wave = tid >> 6, lane = tid & 63, g = lane >> 4, lr = lane & 15;
    int pair = wave >> 1, pw = wave & 1;
    int pid = blockIdx.x, b = blockIdx.y;

    // staging sources (pre-swizzled); per tile: 512 chunks of 16B, 2/thread
    const unsigned short* ksrc[2];
    const unsigned short* vsrc[2];
#pragma unroll
    for (int j = 0; j < 2; ++j) {
        int ci = j * 256 + tid;
        int row = ci >> 3, c = ci & 7, cg = c ^ (row & 7);
        ksrc[j] = Kb + ((size_t)(b * SEQ) + row) * DHEAD + cg * 8;
        vsrc[j] = Vt + ((size_t)(b * DHEAD) + row) * SEQ + cg * 8;
    }

    // stage kv tiles 2s and min(2s+1, n-1) into buf (s&1)
#define STAGE(n_, s_) do {                                                   \
    int te_ = (2 * (s_)) * 64;                                               \
    int to_ = ((2 * (s_) + 1 < (n_)) ? (2 * (s_) + 1) : ((n_) - 1)) * 64;    \
    char* base_ = smem + ((s_) & 1) * 32768;                                 \
    _Pragma("unroll")                                                        \
    for (int j_ = 0; j_ < 2; ++j_) {                                         \
        GLL16(ksrc[j_] + (size_t)te_ * DHEAD, base_ + j_ * 4096 + wave * 1024);          \
        GLL16(ksrc[j_] + (size_t)to_ * DHEAD, base_ + 8192 + j_ * 4096 + wave * 1024);   \
        GLL16(vsrc[j_] + te_, base_ + 16384 + j_ * 4096 + wave * 1024);                  \
        GLL16(vsrc[j_] + to_, base_ + 24576 + j_ * 4096 + wave * 1024);                  \
    } } while (0)

    for (int ql = 0; ql < 2; ++ql) {
        int qt = ql ? (63 - pid) : pid;    // 32-row q-tile id, 0..63
        int n = (qt >> 1) + 1;             // kv tiles of 64 needed
        int nsteps = (n + 1) >> 1;
        int qw = qt * 32 + pw * 16;        // this wave's first q-row
        size_t qrowbase = (size_t)(b * SEQ) + qw;

        bf16x8 aq[2];
#pragma unroll
        for (int kc = 0; kc < 2; ++kc)
            aq[kc] = *(const bf16x8*)&Qb[(qrowbase + lr) * DHEAD + kc * 32 + g * 8];

        if (ql == 0) STAGE(n, 0);   // ql=1 prologue issued in ql=0 epilogue

        float l_part[4];
        f32x4 of[4];
#pragma unroll
        for (int r = 0; r < 4; ++r) l_part[r] = 0.f;
#pragma unroll
        for (int f = 0; f < 4; ++f) of[f] = (f32x4){0.f, 0.f, 0.f, 0.f};

        for (int s = 0; s < nsteps; ++s) {
            if (s + 1 < nsteps) {
                STAGE(n, s + 1);
                asm volatile("s_waitcnt vmcnt(8)" ::: "memory");
            } else {
                asm volatile("s_waitcnt vmcnt(0)" ::: "memory");
            }
            __builtin_amdgcn_s_barrier();
            asm volatile("" ::: "memory");

            int t = 2 * s + pair, kvb = t * 64;
            if (t < n && kvb <= qw + 15) {
                const unsigned short* Kl =
                    (const unsigned short*)(smem + (s & 1) * 32768 + pair * 8192);
                const unsigned short* Vl =
                    (const unsigned short*)(smem + (s & 1) * 32768 + 16384 + pair * 8192);
                unsigned short* Pl = (unsigned short*)(smem + 65536) + wave * 1024;

                // S = Q K^T
                f32x4 s4[4];
#pragma unroll
                for (int f = 0; f < 4; ++f) s4[f] = (f32x4){0.f, 0.f, 0.f, 0.f};
                __builtin_amdgcn_s_setprio(1);
#pragma unroll
                for (int kc = 0; kc < 2; ++kc) {
#pragma unroll
                    for (int f = 0; f < 4; ++f) {
                        int brow = f * 16 + lr;
                        int cb = (kc * 4 + g) ^ (lr & 7);
                        bf16x8 bk = *(const bf16x8*)&Kl[brow * 64 + cb * 8];
                        s4[f] = MFMA16(aq[kc], bk, s4[f]);
                    }
                }
                __builtin_amdgcn_s_setprio(0);

                if (kvb + 63 <= qw) {
#pragma unroll
                    for (int f = 0; f < 4; ++f)
#pragma unroll
                        for (int r = 0; r < 4; ++r) {
                            float p = exp2f(s4[f][r] * ATT_SC2);
                            s4[f][r] = p;
                            l_part[r] += p;
                        }
                } else {
#pragma unroll
                    for (int f = 0; f < 4; ++f) {
                        int kvg = kvb + f * 16 + lr;
#pragma unroll
                        for (int r = 0; r < 4; ++r) {
                            int qr = qw + g * 4 + r;
                            float p = exp2f(s4[f][r] * ATT_SC2);
                            p = (kvg > qr) ? 0.f : p;
                            s4[f][r] = p;
                            l_part[r] += p;
                        }
                    }
                }
                // P -> per-wave LDS (swizzled), bf16
#pragma unroll
                for (int f = 0; f < 4; ++f) {
#pragma unroll
                    for (int r = 0; r < 4; ++r) {
                        int row = g * 4 + r, col = f * 16 + lr;
                        int ch = (col >> 3) ^ (row & 7);
                        Pl[row * 64 + ch * 8 + (col & 7)] = f2bf(s4[f][r]);
                    }
                }
                // O += P V
#pragma unroll
                for (int kc = 0; kc < 2; ++kc) {
                    int cp = (kc * 4 + g) ^ (lr & 7);
                    bf16x8 ap = *(const bf16x8*)&Pl[lr * 64 + cp * 8];
                    __builtin_amdgcn_s_setprio(1);
#pragma unroll
                    for (int fd = 0; fd < 4; ++fd) {
                        int vrow = fd * 16 + lr;
                        int cv = (kc * 4 + g) ^ (lr & 7);
                        bf16x8 bv = *(const bf16x8*)&Vl[vrow * 64 + cv * 8];
                        of[fd] = MFMA16(ap, bv, of[fd]);
                    }
                    __builtin_amdgcn_s_setprio(0);
                }
            }
            asm volatile("" ::: "memory");
            __builtin_amdgcn_s_barrier();
        }

        // ---- epilogue: combine the two pair-partials via LDS ----
        // O buffers [32][68] f32 (padded -> 2-way banks only): pair*8704; l @17408
        {
            float* Obuf = (float*)(smem + pair * 8704);
            float* Ol = (float*)(smem + 17408);
            int row32 = pw * 16 + g * 4;
#pragma unroll
            for (int r = 0; r < 4; ++r) {
                float ls = l_part[r];
                ls += __shfl_xor(ls, 1); ls += __shfl_xor(ls, 2);
                ls += __shfl_xor(ls, 4); ls += __shfl_xor(ls, 8);
                if (lr == 0) Ol[pair * 32 + row32 + r] = ls;
#pragma unroll
                for (int fd = 0; fd < 4; ++fd)
                    Obuf[(row32 + r) * 68 + fd * 16 + lr] = of[fd][r];
            }
        }
        __syncthreads();

        bf16x8 ao[2][2];
        {
            const float* O0 = (const float*)smem;
            const float* O1 = (const float*)(smem + 8704);
            const float* Ol = (const float*)(smem + 17408);
#pragma unroll
            for (int m = 0; m < 2; ++m) {
                int arow = m * 16 + lr;
                float inv = 1.f / (Ol[arow] + Ol[32 + arow]);
#pragma unroll
                for (int kc = 0; kc < 2; ++kc) {
                    int cb = arow * 68 + kc * 32 + g * 8;
                    fl4 xa = *(const fl4*)&O0[cb], xb = *(const fl4*)&O0[cb + 4];
                    fl4 ya = *(const fl4*)&O1[cb], yb = *(const fl4*)&O1[cb + 4];
                    union { unsigned int u[4]; bf16x8 v; } a;
                    a.u[0] = cvtpk((xa[0] + ya[0]) * inv, (xa[1] + ya[1]) * inv);
                    a.u[1] = cvtpk((xa[2] + ya[2]) * inv, (xa[3] + ya[3]) * inv);
                    a.u[2] = cvtpk((xb[0] + yb[0]) * inv, (xb[1] + yb[1]) * inv);
                    a.u[3] = cvtpk((xb[2] + yb[2]) * inv, (xb[3] + yb[3]) * inv);
                    ao[m][kc] = a.v;
                }
            }
        }
        __syncthreads();   // O-region free; safe to restage buf 0

        if (ql == 0) {     // overlap next q-tile's first staging with oproj
            int qt2 = 63 - pid;
            int n2 = (qt2 >> 1) + 1;
            STAGE(n2, 0);
        }

        // ---- output projection: this wave's 256-col slice ----
        {
            int nb = wave * 256;
            f32x4 acc[2][16];
#pragma unroll
            for (int m = 0; m < 2; ++m)
#pragma unroll
                for (int f = 0; f < 16; ++f) acc[m][f] = (f32x4){0.f, 0.f, 0.f, 0.f};
#pragma unroll
            for (int kc = 0; kc < 2; ++kc) {
                __builtin_amdgcn_s_setprio(1);
#pragma unroll
                for (int f = 0; f < 16; ++f) {
                    bf16x8 bw = *(const bf16x8*)
                        &Wob[(size_t)(nb + f * 16 + lr) * DHEAD + kc * 32 + g * 8];
                    acc[0][f] = MFMA16(ao[0][kc], bw, acc[0][f]);
                    acc[1][f] = MFMA16(ao[1][kc], bw, acc[1][f]);
                }
                __builtin_amdgcn_s_setprio(0);
            }
            int mb = b * SEQ + qt * 32;
#pragma unroll
            for (int m = 0; m < 2; ++m) {
                int mrow = mb + m * 16 + g * 4;
#pragma unroll
                for (int f = 0; f < 16; ++f)
#pragma unroll
                    for (int r = 0; r < 4; ++r)
                        out[(size_t)(mrow + r) * DMODEL + nb + f * 16 + lr] = acc[m][f][r];
            }
        }
    }
#undef STAGE
}

extern "C" void kernel_launch(void* const* d_in, const int* in_sizes, int n_in,
                              void* d_out, int out_size, void* d_ws, size_t ws_size,
                              hipStream_t stream) {
    const float* x  = (const float*)d_in[0];
    const float* Wq = (const float*)d_in[1];
    const float* Wk = (const float*)d_in[2];
    const float* Wv = (const float*)d_in[3];
    const float* Wo = (const float*)d_in[4];
    float* out = (float*)d_out;

    unsigned short* Wb  = (unsigned short*)d_ws;   // 192*1024
    unsigned short* Wob = Wb + 196608;             // 1024*64
    unsigned short* Qb  = Wob + 65536;             // 16384*64
    unsigned short* Kb  = Qb + 1048576;
    unsigned short* Vt  = Kb + 1048576;            // [8][64][2048]

    k_cvt<<<256, 256, 0, stream>>>(Wq, Wk, Wv, Wo, Wb, Wob);
    k_qkv<<<256, 256, 0, stream>>>(x, Wb, Qb, Kb, Vt);
    k_fused<<<dim3(32, 8), 256, 0, stream>>>(Qb, Kb, Vt, Wob, out);
}

// Round 8
// 58.055 us; speedup vs baseline: 1.2007x; 1.1649x over previous
//
#include <hip/hip_runtime.h>

#define SEQ 2048
#define DMODEL 1024
#define DHEAD 64
#define NROWS 16384
#define ATT_SC2 0.0450842300667f   // (1/sqrt(1024)) * log2(e), for exp2f

typedef __attribute__((ext_vector_type(8))) short bf16x8;
typedef __attribute__((ext_vector_type(4))) float f32x4;
typedef __attribute__((ext_vector_type(4))) unsigned int u32x4;
typedef __attribute__((ext_vector_type(4))) unsigned short u16x4;
typedef __attribute__((ext_vector_type(4))) float fl4;

#define MFMA16(a,b,c) __builtin_amdgcn_mfma_f32_16x16x32_bf16((a),(b),(c),0,0,0)
#define GLL16(g, l) __builtin_amdgcn_global_load_lds( \
    (const __attribute__((address_space(1))) void*)(g), \
    (__attribute__((address_space(3))) void*)(l), 16, 0, 0)

__device__ __forceinline__ unsigned short f2bf(float f) {
    union { float f; unsigned int u; } v; v.f = f;
    unsigned int u = v.u;
    unsigned int r = u + 0x7fffu + ((u >> 16) & 1u);
    return (unsigned short)(r >> 16);
}

// packed f32x2 -> bf16x2 (RNE) — T12 primitive, no builtin on gfx950
__device__ __forceinline__ unsigned int cvtpk(float lo, float hi) {
    unsigned int d;
    asm volatile("v_cvt_pk_bf16_f32 %0, %1, %2" : "=v"(d) : "v"(lo), "v"(hi));
    return d;
}

// ---------------- kernel 0: convert weights to bf16 ----------------
__global__ __launch_bounds__(256) void k_cvt(
    const float* __restrict__ Wq, const float* __restrict__ Wk,
    const float* __restrict__ Wv, const float* __restrict__ Wo,
    unsigned short* __restrict__ Wb,    // [192][1024] (Wq;Wk;Wv)
    unsigned short* __restrict__ Wob)   // [1024][64]
{
    int i4 = blockIdx.x * 256 + threadIdx.x;
    const int W1 = 16384;
    const float* src; unsigned short* dst; int off;
    if (i4 < 3 * W1) {
        int which = i4 / W1;
        off = i4 - which * W1;
        src = (which == 0) ? Wq : (which == 1) ? Wk : Wv;
        dst = Wb + (size_t)which * 65536;
    } else {
        off = i4 - 3 * W1; src = Wo; dst = Wob;
    }
    fl4 v = reinterpret_cast<const fl4*>(src)[off];
    u16x4 o;
    o[0] = f2bf(v[0]); o[1] = f2bf(v[1]); o[2] = f2bf(v[2]); o[3] = f2bf(v[3]);
    reinterpret_cast<u16x4*>(dst)[off] = o;
}

// ---------------- kernel A: QKV projection, async pipelined ----------------
__global__ __launch_bounds__(256) void k_qkv(
    const float* __restrict__ x,
    const unsigned short* __restrict__ Wb,
    unsigned short* __restrict__ Qb,
    unsigned short* __restrict__ Kb,
    unsigned short* __restrict__ Vt)
{
    __shared__ __align__(16) char smem[81920];

    int tid = threadIdx.x;
    int wave = tid >> 6, lane = tid & 63, g = lane >> 4, lr = lane & 15;
    int mbase = blockIdx.x * 64;

    const float* xsrc[4];
#pragma unroll
    for (int j = 0; j < 4; ++j) {
        int ci = (wave * 4 + j) * 64 + lane;
        int row = ci >> 4, c = ci & 15, cg = c ^ (row & 7);
        xsrc[j] = x + (size_t)(mbase + row) * DMODEL + cg * 4;
    }
    const unsigned short* wsrc[6];
#pragma unroll
    for (int j = 0; j < 6; ++j) {
        int ci = (wave * 6 + j) * 64 + lane;
        int row = ci >> 3, c = ci & 7, cg = c ^ (row & 7);
        wsrc[j] = Wb + (size_t)row * DMODEL + cg * 8;
    }

    f32x4 acc[12];
#pragma unroll
    for (int f = 0; f < 12; ++f) acc[f] = (f32x4){0.f, 0.f, 0.f, 0.f};

#pragma unroll
    for (int j = 0; j < 4; ++j) GLL16(xsrc[j], smem + (wave * 4 + j) * 1024);
#pragma unroll
    for (int j = 0; j < 6; ++j) GLL16(wsrc[j], smem + 32768 + (wave * 6 + j) * 1024);

    for (int ks = 0; ks < 16; ++ks) {
        int cur = ks & 1;
        if (ks < 15) {
            int nb = cur ^ 1;
#pragma unroll
            for (int j = 0; j < 4; ++j)
                GLL16(xsrc[j] + (ks + 1) * 64, smem + nb * 16384 + (wave * 4 + j) * 1024);
#pragma unroll
            for (int j = 0; j < 6; ++j)
                GLL16(wsrc[j] + (ks + 1) * 64, smem + 32768 + nb * 24576 + (wave * 6 + j) * 1024);
            asm volatile("s_waitcnt vmcnt(10)" ::: "memory");
        } else {
            asm volatile("s_waitcnt vmcnt(0)" ::: "memory");
        }
        __builtin_amdgcn_s_barrier();
        asm volatile("" ::: "memory");

        const float* Xf = (const float*)(smem + cur * 16384);
        const unsigned short* Wf = (const unsigned short*)(smem + 32768 + cur * 24576);
        int arow = wave * 16 + lr;
#pragma unroll
        for (int kc = 0; kc < 2; ++kc) {
            int c0 = (kc * 8 + g * 2) ^ (lr & 7);
            int c1 = (kc * 8 + g * 2 + 1) ^ (lr & 7);
            fl4 xa = *(const fl4*)&Xf[arow * 64 + c0 * 4];
            fl4 xb = *(const fl4*)&Xf[arow * 64 + c1 * 4];
            union { unsigned int u[4]; bf16x8 v; } a;
            a.u[0] = cvtpk(xa[0], xa[1]); a.u[1] = cvtpk(xa[2], xa[3]);
            a.u[2] = cvtpk(xb[0], xb[1]); a.u[3] = cvtpk(xb[2], xb[3]);
            __builtin_amdgcn_s_setprio(1);
#pragma unroll
            for (int f = 0; f < 12; ++f) {
                int brow = f * 16 + lr;
                int cb = (kc * 4 + g) ^ (lr & 7);
                bf16x8 b = *(const bf16x8*)&Wf[brow * 64 + cb * 8];
                acc[f] = MFMA16(a.v, b, acc[f]);
            }
            __builtin_amdgcn_s_setprio(0);
        }
        asm volatile("" ::: "memory");
        __builtin_amdgcn_s_barrier();
    }

    int mrow = mbase + wave * 16 + g * 4;
#pragma unroll
    for (int f = 0; f < 8; ++f) {
        int col = f * 16 + lr;
#pragma unroll
        for (int r = 0; r < 4; ++r) {
            unsigned short bv = f2bf(acc[f][r]);
            if (f < 4) Qb[(size_t)(mrow + r) * DHEAD + col] = bv;
            else       Kb[(size_t)(mrow + r) * DHEAD + col - 64] = bv;
        }
    }
    unsigned short* tmp = (unsigned short*)smem;  // [64][72]
#pragma unroll
    for (int f = 8; f < 12; ++f) {
        int h = (f - 8) * 16 + lr;
#pragma unroll
        for (int r = 0; r < 4; ++r)
            tmp[(wave * 16 + g * 4 + r) * 72 + h] = f2bf(acc[f][r]);
    }
    __syncthreads();
    int b = mbase >> 11, sbase = mbase & 2047;
    int h = tid >> 2, sc = tid & 3;
    u32x4 o0, o1;
#pragma unroll
    for (int j = 0; j < 4; ++j) {
        o0[j] = (unsigned int)tmp[(sc * 16 + 2 * j) * 72 + h] |
                ((unsigned int)tmp[(sc * 16 + 2 * j + 1) * 72 + h] << 16);
        o1[j] = (unsigned int)tmp[(sc * 16 + 8 + 2 * j) * 72 + h] |
                ((unsigned int)tmp[(sc * 16 + 9 + 2 * j) * 72 + h] << 16);
    }
    size_t off = ((size_t)(b * 64 + h)) * SEQ + sbase + sc * 16;
    *reinterpret_cast<u32x4*>(&Vt[off]) = o0;
    *reinterpret_cast<u32x4*>(&Vt[off + 8]) = o1;
}

// ---------------- kernel B: fused causal attention + output projection -----
// Grid 512 (flat): bid<256 -> HEAVY qt = 63-(bid>>3); bid>=256 -> LIGHT
// qt = (bid&255)>>3. Round-robin dispatch puts blocks c and c+256 on the
// same CU -> per-CU kv-tile total ~constant (33-34); 2 blocks/CU co-resident
// (LDS 72KB x2 = 144KB <= 160KB) -> 2 waves/SIMD latency hiding.
// Block = 4 waves; wave-pair p computes kv tiles t==p (mod 2) from a shared
// double-buffered 2-tile stage. Fixed-max softmax (exp2), deferred l.
// Epilogue: combine pair partials in LDS, normalize, out = O * Wob^T with
// B-frags straight from L2.
// LDS 72KB: stage 2x32KB @0 (K even/odd, V even/odd), P 8KB @65536.
__global__ __launch_bounds__(256) void k_fused(
    const unsigned short* __restrict__ Qb,
    const unsigned short* __restrict__ Kb,
    const unsigned short* __restrict__ Vt,
    const unsigned short* __restrict__ Wob,
    float* __restrict__ out)
{
    __shared__ __align__(16) char smem[73728];

    int tid = threadIdx.x;
    int wave = tid >> 6, lane = tid & 63, g = lane >> 4, lr = lane & 15;
    int pair = wave >> 1, pw = wave & 1;
    int bid = blockIdx.x;
    int idx = bid & 255;
    int qt = (bid < 256) ? (63 - (idx >> 3)) : (idx >> 3);  // heavy first
    int b = idx & 7;

    // staging sources (pre-swizzled); per tile: 512 chunks of 16B, 2/thread
    const unsigned short* ksrc[2];
    const unsigned short* vsrc[2];
#pragma unroll
    for (int j = 0; j < 2; ++j) {
        int ci = j * 256 + tid;
        int row = ci >> 3, c = ci & 7, cg = c ^ (row & 7);
        ksrc[j] = Kb + ((size_t)(b * SEQ) + row) * DHEAD + cg * 8;
        vsrc[j] = Vt + ((size_t)(b * DHEAD) + row) * SEQ + cg * 8;
    }

    // stage kv tiles 2s and min(2s+1, n-1) into buf (s&1)
#define STAGE(n_, s_) do {                                                   \
    int te_ = (2 * (s_)) * 64;                                               \
    int to_ = ((2 * (s_) + 1 < (n_)) ? (2 * (s_) + 1) : ((n_) - 1)) * 64;    \
    char* base_ = smem + ((s_) & 1) * 32768;                                 \
    _Pragma("unroll")                                                        \
    for (int j_ = 0; j_ < 2; ++j_) {                                         \
        GLL16(ksrc[j_] + (size_t)te_ * DHEAD, base_ + j_ * 4096 + wave * 1024);          \
        GLL16(ksrc[j_] + (size_t)to_ * DHEAD, base_ + 8192 + j_ * 4096 + wave * 1024);   \
        GLL16(vsrc[j_] + te_, base_ + 16384 + j_ * 4096 + wave * 1024);                  \
        GLL16(vsrc[j_] + to_, base_ + 24576 + j_ * 4096 + wave * 1024);                  \
    } } while (0)

    int n = (qt >> 1) + 1;             // kv tiles of 64 needed
    int nsteps = (n + 1) >> 1;
    int qw = qt * 32 + pw * 16;        // this wave's first q-row
    size_t qrowbase = (size_t)(b * SEQ) + qw;

    bf16x8 aq[2];
#pragma unroll
    for (int kc = 0; kc < 2; ++kc)
        aq[kc] = *(const bf16x8*)&Qb[(qrowbase + lr) * DHEAD + kc * 32 + g * 8];

    STAGE(n, 0);

    float l_part[4];
    f32x4 of[4];
#pragma unroll
    for (int r = 0; r < 4; ++r) l_part[r] = 0.f;
#pragma unroll
    for (int f = 0; f < 4; ++f) of[f] = (f32x4){0.f, 0.f, 0.f, 0.f};

    for (int s = 0; s < nsteps; ++s) {
        if (s + 1 < nsteps) {
            STAGE(n, s + 1);
            asm volatile("s_waitcnt vmcnt(8)" ::: "memory");
        } else {
            asm volatile("s_waitcnt vmcnt(0)" ::: "memory");
        }
        __builtin_amdgcn_s_barrier();
        asm volatile("" ::: "memory");

        int t = 2 * s + pair, kvb = t * 64;
        if (t < n && kvb <= qw + 15) {
            const unsigned short* Kl =
                (const unsigned short*)(smem + (s & 1) * 32768 + pair * 8192);
            const unsigned short* Vl =
                (const unsigned short*)(smem + (s & 1) * 32768 + 16384 + pair * 8192);
            unsigned short* Pl = (unsigned short*)(smem + 65536) + wave * 1024;

            // S = Q K^T
            f32x4 s4[4];
#pragma unroll
            for (int f = 0; f < 4; ++f) s4[f] = (f32x4){0.f, 0.f, 0.f, 0.f};
            __builtin_amdgcn_s_setprio(1);
#pragma unroll
            for (int kc = 0; kc < 2; ++kc) {
#pragma unroll
                for (int f = 0; f < 4; ++f) {
                    int brow = f * 16 + lr;
                    int cb = (kc * 4 + g) ^ (lr & 7);
                    bf16x8 bk = *(const bf16x8*)&Kl[brow * 64 + cb * 8];
                    s4[f] = MFMA16(aq[kc], bk, s4[f]);
                }
            }
            __builtin_amdgcn_s_setprio(0);

            if (kvb + 63 <= qw) {
#pragma unroll
                for (int f = 0; f < 4; ++f)
#pragma unroll
                    for (int r = 0; r < 4; ++r) {
                        float p = exp2f(s4[f][r] * ATT_SC2);
                        s4[f][r] = p;
                        l_part[r] += p;
                    }
            } else {
#pragma unroll
                for (int f = 0; f < 4; ++f) {
                    int kvg = kvb + f * 16 + lr;
#pragma unroll
                    for (int r = 0; r < 4; ++r) {
                        int qr = qw + g * 4 + r;
                        float p = exp2f(s4[f][r] * ATT_SC2);
                        p = (kvg > qr) ? 0.f : p;
                        s4[f][r] = p;
                        l_part[r] += p;
                    }
                }
            }
            // P -> per-wave LDS (swizzled), bf16
#pragma unroll
            for (int f = 0; f < 4; ++f) {
#pragma unroll
                for (int r = 0; r < 4; ++r) {
                    int row = g * 4 + r, col = f * 16 + lr;
                    int ch = (col >> 3) ^ (row & 7);
                    Pl[row * 64 + ch * 8 + (col & 7)] = f2bf(s4[f][r]);
                }
            }
            // O += P V
#pragma unroll
            for (int kc = 0; kc < 2; ++kc) {
                int cp = (kc * 4 + g) ^ (lr & 7);
                bf16x8 ap = *(const bf16x8*)&Pl[lr * 64 + cp * 8];
                __builtin_amdgcn_s_setprio(1);
#pragma unroll
                for (int fd = 0; fd < 4; ++fd) {
                    int vrow = fd * 16 + lr;
                    int cv = (kc * 4 + g) ^ (lr & 7);
                    bf16x8 bv = *(const bf16x8*)&Vl[vrow * 64 + cv * 8];
                    of[fd] = MFMA16(ap, bv, of[fd]);
                }
                __builtin_amdgcn_s_setprio(0);
            }
        }
        asm volatile("" ::: "memory");
        __builtin_amdgcn_s_barrier();
    }

    // ---- epilogue: combine the two pair-partials via LDS ----
    // O buffers [32][68] f32 (padded): pair*8704; l @17408
    {
        float* Obuf = (float*)(smem + pair * 8704);
        float* Ol = (float*)(smem + 17408);
        int row32 = pw * 16 + g * 4;
#pragma unroll
        for (int r = 0; r < 4; ++r) {
            float ls = l_part[r];
            ls += __shfl_xor(ls, 1); ls += __shfl_xor(ls, 2);
            ls += __shfl_xor(ls, 4); ls += __shfl_xor(ls, 8);
            if (lr == 0) Ol[pair * 32 + row32 + r] = ls;
#pragma unroll
            for (int fd = 0; fd < 4; ++fd)
                Obuf[(row32 + r) * 68 + fd * 16 + lr] = of[fd][r];
        }
    }
    __syncthreads();

    bf16x8 ao[2][2];
    {
        const float* O0 = (const float*)smem;
        const float* O1 = (const float*)(smem + 8704);
        const float* Ol = (const float*)(smem + 17408);
#pragma unroll
        for (int m = 0; m < 2; ++m) {
            int arow = m * 16 + lr;
            float inv = 1.f / (Ol[arow] + Ol[32 + arow]);
#pragma unroll
            for (int kc = 0; kc < 2; ++kc) {
                int cb = arow * 68 + kc * 32 + g * 8;
                fl4 xa = *(const fl4*)&O0[cb], xb = *(const fl4*)&O0[cb + 4];
                fl4 ya = *(const fl4*)&O1[cb], yb = *(const fl4*)&O1[cb + 4];
                union { unsigned int u[4]; bf16x8 v; } a;
                a.u[0] = cvtpk((xa[0] + ya[0]) * inv, (xa[1] + ya[1]) * inv);
                a.u[1] = cvtpk((xa[2] + ya[2]) * inv, (xa[3] + ya[3]) * inv);
                a.u[2] = cvtpk((xb[0] + yb[0]) * inv, (xb[1] + yb[1]) * inv);
                a.u[3] = cvtpk((xb[2] + yb[2]) * inv, (xb[3] + yb[3]) * inv);
                ao[m][kc] = a.v;
            }
        }
    }

    // ---- output projection: this wave's 256-col slice ----
    {
        int nb = wave * 256;
        f32x4 acc[2][16];
#pragma unroll
        for (int m = 0; m < 2; ++m)
#pragma unroll
            for (int f = 0; f < 16; ++f) acc[m][f] = (f32x4){0.f, 0.f, 0.f, 0.f};
#pragma unroll
        for (int kc = 0; kc < 2; ++kc) {
            __builtin_amdgcn_s_setprio(1);
#pragma unroll
            for (int f = 0; f < 16; ++f) {
                bf16x8 bw = *(const bf16x8*)
                    &Wob[(size_t)(nb + f * 16 + lr) * DHEAD + kc * 32 + g * 8];
                acc[0][f] = MFMA16(ao[0][kc], bw, acc[0][f]);
                acc[1][f] = MFMA16(ao[1][kc], bw, acc[1][f]);
            }
            __builtin_amdgcn_s_setprio(0);
        }
        int mb = b * SEQ + qt * 32;
#pragma unroll
        for (int m = 0; m < 2; ++m) {
            int mrow = mb + m * 16 + g * 4;
#pragma unroll
            for (int f = 0; f < 16; ++f)
#pragma unroll
                for (int r = 0; r < 4; ++r)
                    out[(size_t)(mrow + r) * DMODEL + nb + f * 16 + lr] = acc[m][f][r];
        }
    }
#undef STAGE
}

extern "C" void kernel_launch(void* const* d_in, const int* in_sizes, int n_in,
                              void* d_out, int out_size, void* d_ws, size_t ws_size,
                              hipStream_t stream) {
    const float* x  = (const float*)d_in[0];
    const float* Wq = (const float*)d_in[1];
    const float* Wk = (const float*)d_in[2];
    const float* Wv = (const float*)d_in[3];
    const float* Wo = (const float*)d_in[4];
    float* out = (float*)d_out;

    unsigned short* Wb  = (unsigned short*)d_ws;   // 192*1024
    unsigned short* Wob = Wb + 196608;             // 1024*64
    unsigned short* Qb  = Wob + 65536;             // 16384*64
    unsigned short* Kb  = Qb + 1048576;
    unsigned short* Vt  = Kb + 1048576;            // [8][64][2048]

    k_cvt<<<256, 256, 0, stream>>>(Wq, Wk, Wv, Wo, Wb, Wob);
    k_qkv<<<256, 256, 0, stream>>>(x, Wb, Qb, Kb, Vt);
    k_fused<<<512, 256, 0, stream>>>(Qb, Kb, Vt, Wob, out);
}

// Round 9
// 55.402 us; speedup vs baseline: 1.2582x; 1.0479x over previous
//
#include <hip/hip_runtime.h>

#define SEQ 2048
#define DMODEL 1024
#define DHEAD 64
#define NROWS 16384
#define ATT_SC2 0.0450842300667f   // (1/sqrt(1024)) * log2(e), for exp2f

typedef __attribute__((ext_vector_type(8))) short bf16x8;
typedef __attribute__((ext_vector_type(4))) float f32x4;
typedef __attribute__((ext_vector_type(4))) unsigned int u32x4;
typedef __attribute__((ext_vector_type(4))) unsigned short u16x4;
typedef __attribute__((ext_vector_type(4))) float fl4;

#define MFMA16(a,b,c) __builtin_amdgcn_mfma_f32_16x16x32_bf16((a),(b),(c),0,0,0)
#define GLL16(g, l) __builtin_amdgcn_global_load_lds( \
    (const __attribute__((address_space(1))) void*)(g), \
    (__attribute__((address_space(3))) void*)(l), 16, 0, 0)

__device__ __forceinline__ unsigned short f2bf(float f) {
    union { float f; unsigned int u; } v; v.f = f;
    unsigned int u = v.u;
    unsigned int r = u + 0x7fffu + ((u >> 16) & 1u);
    return (unsigned short)(r >> 16);
}

// packed f32x2 -> bf16x2 (RNE)
__device__ __forceinline__ unsigned int cvtpk(float lo, float hi) {
    unsigned int d;
    asm volatile("v_cvt_pk_bf16_f32 %0, %1, %2" : "=v"(d) : "v"(lo), "v"(hi));
    return d;
}

// ---------------- kernel 0: convert weights to bf16 ----------------
__global__ __launch_bounds__(256) void k_cvt(
    const float* __restrict__ Wq, const float* __restrict__ Wk,
    const float* __restrict__ Wv, const float* __restrict__ Wo,
    unsigned short* __restrict__ Wb,    // [192][1024] (Wq;Wk;Wv)
    unsigned short* __restrict__ Wob)   // [1024][64]
{
    int i4 = blockIdx.x * 256 + threadIdx.x;
    const int W1 = 16384;
    const float* src; unsigned short* dst; int off;
    if (i4 < 3 * W1) {
        int which = i4 / W1;
        off = i4 - which * W1;
        src = (which == 0) ? Wq : (which == 1) ? Wk : Wv;
        dst = Wb + (size_t)which * 65536;
    } else {
        off = i4 - 3 * W1; src = Wo; dst = Wob;
    }
    fl4 v = reinterpret_cast<const fl4*>(src)[off];
    u16x4 o;
    o[0] = f2bf(v[0]); o[1] = f2bf(v[1]); o[2] = f2bf(v[2]); o[3] = f2bf(v[3]);
    reinterpret_cast<u16x4*>(dst)[off] = o;
}

// ---------------- kernel A: QKV projection ----------------
// 32-row M-blocks, grid 512 (2 blocks/CU). Waves: (mh = wave&1) 16-row
// m-slice x (nh = wave>>1) 96-col N-slice. LDS 64KB: x 2x8KB @0 (fp32,
// pre-swizzled src), W 2x24KB @16384.
__global__ __launch_bounds__(256) void k_qkv(
    const float* __restrict__ x,
    const unsigned short* __restrict__ Wb,
    unsigned short* __restrict__ Qb,
    unsigned short* __restrict__ Kb,
    unsigned short* __restrict__ Vt)
{
    __shared__ __align__(16) char smem[65536];

    int tid = threadIdx.x;
    int wave = tid >> 6, lane = tid & 63, g = lane >> 4, lr = lane & 15;
    int mh = wave & 1, nh = wave >> 1;
    int mbase = blockIdx.x * 32;

    const float* xsrc[2];
#pragma unroll
    for (int j = 0; j < 2; ++j) {
        int ci = j * 256 + tid;
        int row = ci >> 4, c = ci & 15, cg = c ^ (row & 7);
        xsrc[j] = x + (size_t)(mbase + row) * DMODEL + cg * 4;
    }
    const unsigned short* wsrc[6];
#pragma unroll
    for (int j = 0; j < 6; ++j) {
        int ci = (wave * 6 + j) * 64 + lane;
        int row = ci >> 3, c = ci & 7, cg = c ^ (row & 7);
        wsrc[j] = Wb + (size_t)row * DMODEL + cg * 8;
    }

    f32x4 acc[6];
#pragma unroll
    for (int f = 0; f < 6; ++f) acc[f] = (f32x4){0.f, 0.f, 0.f, 0.f};

#pragma unroll
    for (int j = 0; j < 2; ++j) GLL16(xsrc[j], smem + j * 4096 + wave * 1024);
#pragma unroll
    for (int j = 0; j < 6; ++j) GLL16(wsrc[j], smem + 16384 + (wave * 6 + j) * 1024);

    for (int ks = 0; ks < 16; ++ks) {
        int cur = ks & 1;
        if (ks < 15) {
            int nb = cur ^ 1;
#pragma unroll
            for (int j = 0; j < 2; ++j)
                GLL16(xsrc[j] + (ks + 1) * 64, smem + nb * 8192 + j * 4096 + wave * 1024);
#pragma unroll
            for (int j = 0; j < 6; ++j)
                GLL16(wsrc[j] + (ks + 1) * 64,
                      smem + 16384 + nb * 24576 + (wave * 6 + j) * 1024);
            asm volatile("s_waitcnt vmcnt(8)" ::: "memory");
        } else {
            asm volatile("s_waitcnt vmcnt(0)" ::: "memory");
        }
        __builtin_amdgcn_s_barrier();
        asm volatile("" ::: "memory");

        const float* Xf = (const float*)(smem + cur * 8192);
        const unsigned short* Wf = (const unsigned short*)(smem + 16384 + cur * 24576);
        int arow = mh * 16 + lr;   // arow&7 == lr&7
#pragma unroll
        for (int kc = 0; kc < 2; ++kc) {
            int c0 = (kc * 8 + g * 2) ^ (lr & 7);
            int c1 = (kc * 8 + g * 2 + 1) ^ (lr & 7);
            fl4 xa = *(const fl4*)&Xf[arow * 64 + c0 * 4];
            fl4 xb = *(const fl4*)&Xf[arow * 64 + c1 * 4];
            union { unsigned int u[4]; bf16x8 v; } a;
            a.u[0] = cvtpk(xa[0], xa[1]); a.u[1] = cvtpk(xa[2], xa[3]);
            a.u[2] = cvtpk(xb[0], xb[1]); a.u[3] = cvtpk(xb[2], xb[3]);
            __builtin_amdgcn_s_setprio(1);
#pragma unroll
            for (int f = 0; f < 6; ++f) {
                int brow = (nh * 6 + f) * 16 + lr;
                int cb = (kc * 4 + g) ^ (lr & 7);
                bf16x8 b = *(const bf16x8*)&Wf[brow * 64 + cb * 8];
                acc[f] = MFMA16(a.v, b, acc[f]);
            }
            __builtin_amdgcn_s_setprio(0);
        }
        asm volatile("" ::: "memory");
        __builtin_amdgcn_s_barrier();
    }

    // epilogue: Q,K direct; V via LDS repack -> Vt[b][h][s]
    unsigned short* tmp = (unsigned short*)smem;  // [32][72]
    int mrow = mbase + mh * 16 + g * 4;
#pragma unroll
    for (int f = 0; f < 6; ++f) {
        int fg = nh * 6 + f;
#pragma unroll
        for (int r = 0; r < 4; ++r) {
            unsigned short bv = f2bf(acc[f][r]);
            if (fg < 4)      Qb[(size_t)(mrow + r) * DHEAD + fg * 16 + lr] = bv;
            else if (fg < 8) Kb[(size_t)(mrow + r) * DHEAD + (fg - 4) * 16 + lr] = bv;
            else             tmp[(mh * 16 + g * 4 + r) * 72 + (fg - 8) * 16 + lr] = bv;
        }
    }
    __syncthreads();
    int b = mbase >> 11, sbase = mbase & 2047;
    int h = tid >> 2, sc = tid & 3;
    u32x4 o;
#pragma unroll
    for (int j = 0; j < 4; ++j) {
        o[j] = (unsigned int)tmp[(sc * 8 + 2 * j) * 72 + h] |
               ((unsigned int)tmp[(sc * 8 + 2 * j + 1) * 72 + h] << 16);
    }
    size_t off = ((size_t)(b * 64 + h)) * SEQ + sbase + sc * 8;
    *reinterpret_cast<u32x4*>(&Vt[off]) = o;
}

// ---------------- kernel B: fused attention + output projection ----------
// R8 structure (grid 512, heavy/light pairing, wave-pair kv parity split,
// 2-tile double-buffered stage) with the P LDS round-trip replaced by
// swapped QK^T + cvt_pk + permlane16/32_swap in-register redistribution.
// LDS 64KB: stage 2x32KB (K even/odd 8K+8K, V even/odd 8K+8K); epilogue
// Obuf/Ol reuse stage region.
__global__ __launch_bounds__(256) void k_fused(
    const unsigned short* __restrict__ Qb,
    const unsigned short* __restrict__ Kb,
    const unsigned short* __restrict__ Vt,
    const unsigned short* __restrict__ Wob,
    float* __restrict__ out)
{
    __shared__ __align__(16) char smem[65536];

    int tid = threadIdx.x;
    int wave = tid >> 6, lane = tid & 63, g = lane >> 4, lr = lane & 15;
    int pair = wave >> 1, pw = wave & 1;
    int bid = blockIdx.x;
    int idx = bid & 255;
    int qt = (bid < 256) ? (63 - (idx >> 3)) : (idx >> 3);  // heavy first
    int b = idx & 7;

    const unsigned short* ksrc[2];
    const unsigned short* vsrc[2];
#pragma unroll
    for (int j = 0; j < 2; ++j) {
        int ci = j * 256 + tid;
        int row = ci >> 3, c = ci & 7, cg = c ^ (row & 7);
        ksrc[j] = Kb + ((size_t)(b * SEQ) + row) * DHEAD + cg * 8;
        vsrc[j] = Vt + ((size_t)(b * DHEAD) + row) * SEQ + cg * 8;
    }

#define STAGE(n_, s_) do {                                                   \
    int te_ = (2 * (s_)) * 64;                                               \
    int to_ = ((2 * (s_) + 1 < (n_)) ? (2 * (s_) + 1) : ((n_) - 1)) * 64;    \
    char* base_ = smem + ((s_) & 1) * 32768;                                 \
    _Pragma("unroll")                                                        \
    for (int j_ = 0; j_ < 2; ++j_) {                                         \
        GLL16(ksrc[j_] + (size_t)te_ * DHEAD, base_ + j_ * 4096 + wave * 1024);          \
        GLL16(ksrc[j_] + (size_t)to_ * DHEAD, base_ + 8192 + j_ * 4096 + wave * 1024);   \
        GLL16(vsrc[j_] + te_, base_ + 16384 + j_ * 4096 + wave * 1024);                  \
        GLL16(vsrc[j_] + to_, base_ + 24576 + j_ * 4096 + wave * 1024);                  \
    } } while (0)

    int n = (qt >> 1) + 1;
    int nsteps = (n + 1) >> 1;
    int qw = qt * 32 + pw * 16;
    size_t qrowbase = (size_t)(b * SEQ) + qw;

    bf16x8 aq[2];
#pragma unroll
    for (int kc = 0; kc < 2; ++kc)
        aq[kc] = *(const bf16x8*)&Qb[(qrowbase + lr) * DHEAD + kc * 32 + g * 8];

    STAGE(n, 0);

    float l_part = 0.f;
    f32x4 of[4];
#pragma unroll
    for (int f = 0; f < 4; ++f) of[f] = (f32x4){0.f, 0.f, 0.f, 0.f};

    for (int s = 0; s < nsteps; ++s) {
        if (s + 1 < nsteps) {
            STAGE(n, s + 1);
            asm volatile("s_waitcnt vmcnt(8)" ::: "memory");
        } else {
            asm volatile("s_waitcnt vmcnt(0)" ::: "memory");
        }
        __builtin_amdgcn_s_barrier();
        asm volatile("" ::: "memory");

        int t = 2 * s + pair, kvb = t * 64;
        if (t < n && kvb <= qw + 15) {   // wave-uniform skip
            const unsigned short* Kl =
                (const unsigned short*)(smem + (s & 1) * 32768 + pair * 8192);
            const unsigned short* Vl =
                (const unsigned short*)(smem + (s & 1) * 32768 + 16384 + pair * 8192);

            // swapped S = K Q^T : lane holds S[kv=f*16+g*4+r][q=lr]
            f32x4 s4[4];
#pragma unroll
            for (int f = 0; f < 4; ++f) s4[f] = (f32x4){0.f, 0.f, 0.f, 0.f};
            __builtin_amdgcn_s_setprio(1);
#pragma unroll
            for (int kc = 0; kc < 2; ++kc) {
#pragma unroll
                for (int f = 0; f < 4; ++f) {
                    int brow = f * 16 + lr;
                    int cb = (kc * 4 + g) ^ (lr & 7);
                    bf16x8 bk = *(const bf16x8*)&Kl[brow * 64 + cb * 8];
                    s4[f] = MFMA16(bk, aq[kc], s4[f]);
                }
            }
            __builtin_amdgcn_s_setprio(0);

            if (kvb + 63 <= qw) {
#pragma unroll
                for (int f = 0; f < 4; ++f)
#pragma unroll
                    for (int r = 0; r < 4; ++r) {
                        float p = exp2f(s4[f][r] * ATT_SC2);
                        s4[f][r] = p;
                        l_part += p;
                    }
            } else {
                int qr = qw + lr;
#pragma unroll
                for (int f = 0; f < 4; ++f) {
#pragma unroll
                    for (int r = 0; r < 4; ++r) {
                        int kvg = kvb + f * 16 + g * 4 + r;
                        float p = exp2f(s4[f][r] * ATT_SC2);
                        p = (kvg > qr) ? 0.f : p;
                        s4[f][r] = p;
                        l_part += p;
                    }
                }
            }
            // pack P to bf16 pairs: pk[f][h] = (kv=f*16+g*4+2h, +1) for q=lr
            unsigned int pk[4][2];
#pragma unroll
            for (int f = 0; f < 4; ++f) {
                pk[f][0] = cvtpk(s4[f][0], s4[f][1]);
                pk[f][1] = cvtpk(s4[f][2], s4[f][3]);
            }
            // redistribute to A-frag via permlane swaps; O += P V
#pragma unroll
            for (int kc = 0; kc < 2; ++kc) {
                unsigned int A = pk[2 * kc][0],     Bv = pk[2 * kc][1];
                unsigned int C = pk[2 * kc + 1][0], D  = pk[2 * kc + 1][1];
                asm("v_permlane32_swap_b32 %0, %1" : "+v"(A), "+v"(C));
                asm("v_permlane16_swap_b32 %0, %1" : "+v"(A), "+v"(C));
                asm("v_permlane32_swap_b32 %0, %1" : "+v"(Bv), "+v"(D));
                asm("v_permlane16_swap_b32 %0, %1" : "+v"(Bv), "+v"(D));
                union { unsigned int u[4]; bf16x8 v; } ap;
                ap.u[0] = A; ap.u[1] = Bv; ap.u[2] = C; ap.u[3] = D;
                __builtin_amdgcn_s_setprio(1);
#pragma unroll
                for (int fd = 0; fd < 4; ++fd) {
                    int vrow = fd * 16 + lr;
                    int cv = (kc * 4 + g) ^ (lr & 7);
                    bf16x8 bv = *(const bf16x8*)&Vl[vrow * 64 + cv * 8];
                    of[fd] = MFMA16(ap.v, bv, of[fd]);
                }
                __builtin_amdgcn_s_setprio(0);
            }
        }
        asm volatile("" ::: "memory");
        __builtin_amdgcn_s_barrier();
    }

    // ---- epilogue: combine pair partials via LDS (reuses stage region) ----
    {
        float* Obuf = (float*)(smem + pair * 8704);   // [32][68] per pair
        float* Ol = (float*)(smem + 17408);           // [2][32]
        float ls = l_part;
        ls += __shfl_xor(ls, 16);
        ls += __shfl_xor(ls, 32);
        if (lane < 16) Ol[pair * 32 + pw * 16 + lane] = ls;
        int row32 = pw * 16 + g * 4;
#pragma unroll
        for (int r = 0; r < 4; ++r)
#pragma unroll
            for (int fd = 0; fd < 4; ++fd)
                Obuf[(row32 + r) * 68 + fd * 16 + lr] = of[fd][r];
    }
    __syncthreads();

    bf16x8 ao[2][2];
    {
        const float* O0 = (const float*)smem;
        const float* O1 = (const float*)(smem + 8704);
        const float* Ol = (const float*)(smem + 17408);
#pragma unroll
        for (int m = 0; m < 2; ++m) {
            int arow = m * 16 + lr;
            float inv = 1.f / (Ol[arow] + Ol[32 + arow]);
#pragma unroll
            for (int kc = 0; kc < 2; ++kc) {
                int cb = arow * 68 + kc * 32 + g * 8;
                fl4 xa = *(const fl4*)&O0[cb], xb = *(const fl4*)&O0[cb + 4];
                fl4 ya = *(const fl4*)&O1[cb], yb = *(const fl4*)&O1[cb + 4];
                union { unsigned int u[4]; bf16x8 v; } a;
                a.u[0] = cvtpk((xa[0] + ya[0]) * inv, (xa[1] + ya[1]) * inv);
                a.u[1] = cvtpk((xa[2] + ya[2]) * inv, (xa[3] + ya[3]) * inv);
                a.u[2] = cvtpk((xb[0] + yb[0]) * inv, (xb[1] + yb[1]) * inv);
                a.u[3] = cvtpk((xb[2] + yb[2]) * inv, (xb[3] + yb[3]) * inv);
                ao[m][kc] = a.v;
            }
        }
    }

    // ---- output projection: this wave's 256-col slice ----
    {
        int nb = wave * 256;
        f32x4 acc[2][16];
#pragma unroll
        for (int m = 0; m < 2; ++m)
#pragma unroll
            for (int f = 0; f < 16; ++f) acc[m][f] = (f32x4){0.f, 0.f, 0.f, 0.f};
#pragma unroll
        for (int kc = 0; kc < 2; ++kc) {
            __builtin_amdgcn_s_setprio(1);
#pragma unroll
            for (int f = 0; f < 16; ++f) {
                bf16x8 bw = *(const bf16x8*)
                    &Wob[(size_t)(nb + f * 16 + lr) * DHEAD + kc * 32 + g * 8];
                acc[0][f] = MFMA16(ao[0][kc], bw, acc[0][f]);
                acc[1][f] = MFMA16(ao[1][kc], bw, acc[1][f]);
            }
            __builtin_amdgcn_s_setprio(0);
        }
        int mb = b * SEQ + qt * 32;
#pragma unroll
        for (int m = 0; m < 2; ++m) {
            int mrow = mb + m * 16 + g * 4;
#pragma unroll
            for (int f = 0; f < 16; ++f)
#pragma unroll
                for (int r = 0; r < 4; ++r)
                    out[(size_t)(mrow + r) * DMODEL + nb + f * 16 + lr] = acc[m][f][r];
        }
    }
#undef STAGE
}

extern "C" void kernel_launch(void* const* d_in, const int* in_sizes, int n_in,
                              void* d_out, int out_size, void* d_ws, size_t ws_size,
                              hipStream_t stream) {
    const float* x  = (const float*)d_in[0];
    const float* Wq = (const float*)d_in[1];
    const float* Wk = (const float*)d_in[2];
    const float* Wv = (const float*)d_in[3];
    const float* Wo = (const float*)d_in[4];
    float* out = (float*)d_out;

    unsigned short* Wb  = (unsigned short*)d_ws;   // 192*1024
    unsigned short* Wob = Wb + 196608;             // 1024*64
    unsigned short* Qb  = Wob + 65536;             // 16384*64
    unsigned short* Kb  = Qb + 1048576;
    unsigned short* Vt  = Kb + 1048576;            // [8][64][2048]

    k_cvt<<<256, 256, 0, stream>>>(Wq, Wk, Wv, Wo, Wb, Wob);
    k_qkv<<<512, 256, 0, stream>>>(x, Wb, Qb, Kb, Vt);
    k_fused<<<512, 256, 0, stream>>>(Qb, Kb, Vt, Wob, out);
}